// Round 8
// baseline (154.847 us; speedup 1.0000x reference)
//
#include <hip/hip_runtime.h>
#include <cstdint>
#include <cstddef>
#include <type_traits>

#define B_ROWS 16384
#define D_DIM  512
#define O_DIM  512
#define BM 64
#define BN 512
#define BK 32
// W repacked fragment-major: Wf[tIdx=f*16+c][cb=o/16][lane][8 bf16]
// (tIdx<144, cb<32, lane<64). A wave's B-fragment (16 cols x 8 k) is the
// contiguous 1KB chunk at ((tIdx*32+cb)*64)*8 -- one coalesced
// global_load_dwordx4 per lane, straight to VGPR.

typedef __bf16 bf16;
typedef __attribute__((ext_vector_type(8))) bf16  bf16x8;
typedef __attribute__((ext_vector_type(4))) float f32x4;

__device__ __forceinline__ uint32_t pk2(float a, float b) {
    uint16_t ua = __builtin_bit_cast(uint16_t, (__bf16)a);
    uint16_t ub = __builtin_bit_cast(uint16_t, (__bf16)b);
    return (uint32_t)ua | ((uint32_t)ub << 16);
}

// Spline channels b0..b7 for one element as 4 packed bf16 pair-regs.
__device__ __forceinline__ void spline_pairs(float xv, uint32_t out[4]) {
    float xn = fminf(fmaxf(xv, -2.0f), 2.0f);
    float t  = (xn + 3.2f) * 2.5f;        // in [3,13]
    int   j0 = (int)t;                    // t>0 so trunc==floor
    float u  = t - (float)j0;
    float u2 = u * u, u3 = u2 * u, omu = 1.0f - u;
    const float s6 = 1.0f / 6.0f;
    float w0 = omu * omu * omu * s6;
    float w1 = (3.0f * u3 - 6.0f * u2 + 4.0f) * s6;
    float w2 = (-3.0f * u3 + 3.0f * u2 + 3.0f * u + 1.0f) * s6;
    float w3 = u3 * s6;
    uint64_t W64 = ((uint64_t)pk2(w2, w3) << 32) | pk2(w0, w1);
    int sh = (j0 - 3) * 16;               // 0..160
    uint64_t lo = W64 << (sh & 63);
    uint64_t hi = W64 >> ((64 - sh) & 63);
    uint32_t lo_lo = (uint32_t)lo, lo_hi = (uint32_t)(lo >> 32);
    uint32_t hi_lo = (uint32_t)hi, hi_hi = (uint32_t)(hi >> 32);
    bool lt64 = sh < 64, eq0 = (sh == 0), lt128 = sh < 128;
    out[0] = lt64 ? lo_lo : 0u;
    out[1] = lt64 ? lo_hi : 0u;
    out[2] = lt64 ? (eq0 ? 0u : hi_lo) : (lt128 ? lo_lo : 0u);
    out[3] = lt64 ? (eq0 ? 0u : hi_hi) : (lt128 ? lo_hi : 0u);
}

// base_weight[O,D] + spline_weight[O,D,8] fp32 -> frag-major Wf (bf16).
__global__ void pack_w_kernel(const float* __restrict__ bw,
                              const float* __restrict__ sw,
                              bf16* __restrict__ W) {
    int idx = blockIdx.x * blockDim.x + threadIdx.x;   // over O*64
    if (idx >= O_DIM * 64) return;
    int o  = idx >> 6;
    int i0 = (idx & 63) * 8;

    bf16 ob[9][8];
    const float* bwp = bw + (size_t)o * D_DIM + i0;
#pragma unroll
    for (int e = 0; e < 8; e++) {
        ob[0][e] = (bf16)bwp[e];
        const float* sp = sw + ((size_t)o * D_DIM + i0 + e) * 8;
#pragma unroll
        for (int c = 0; c < 8; c++)
            ob[c + 1][e] = (bf16)sp[c];
    }
    const int c   = i0 >> 5;              // k-chunk within channel
    const int sub = (i0 & 31) >> 3;       // quad (k-block within chunk)
    const int cb  = o >> 4;
    const int ln  = (o & 15) + sub * 16;
#pragma unroll
    for (int f = 0; f < 9; f++) {
        size_t off = ((size_t)((f * 16 + c) * 32 + cb) * 64 + ln) * 8;
        *(bf16x8*)(W + off) = *(const bf16x8*)ob[f];
    }
}

// As-only barrier: drain LDS ops, then barrier (B lives in VGPRs).
#define BARA asm volatile("s_waitcnt lgkmcnt(0)\n\ts_barrier" ::: "memory")

// R16: TLP instead of ILP. R15 (deeper pipelining) was exactly neutral;
// all pipes <45% busy at 2 waves/SIMD in lockstep -> latency-bound, no
// wave available to fill dependency holes. Now 1024 threads = 16 waves =
// 4 waves/SIMD, 1 block/CU, wave tile 64x32 (im4 x jn2). Traffic: B@L2
// unchanged (32KB/CU/step), featurize unchanged (2 elems/thread), only
// LDS A-reads double (64KB/step ~ 750cyc, still < the 1350 wall).
// Structure = R14: As 4 slabs write-dist 2, B dbuf dist 1, barrier every
// 2 steps, lgkm-only. k-order & per-output accumulation order unchanged
// -> absmax identical.
__global__ __launch_bounds__(1024, 4)
void gemm_fused_kernel(const float* __restrict__ x, const bf16* __restrict__ Wf,
                       float* __restrict__ C) {
    __shared__ __align__(16) bf16 As0[BM * BK], As1[BM * BK], As2[BM * BK], As3[BM * BK];

    const int tid  = threadIdx.x;
    const int bid  = blockIdx.x;
    const int m0   = bid * BM;
    const int wave = tid >> 6;
    const int lane = tid & 63;
    const int wn   = wave * 32;          // 16 waves cover N=512
    const int l15  = lane & 15;
    const int quad = lane >> 4;
    const int swz  = (l15 >> 1) & 3;
    const int aoff = l15 * BK + (quad ^ swz) * 8;

    // featurize: thread owns (row rA, 2 i's at sixteenth q2 of the 32-chunk)
    const int rA = tid >> 4;             // 0..63
    const int q2 = tid & 15;             // 0..15
    const float* xrow = x + (size_t)(m0 + rA) * D_DIM + q2 * 2;
    // 4B write: slot (q2>>2) XOR-swizzled to match aoff read swizzle,
    // sub-offset (q2&3)*2 within the 8-elem slot
    const int awo = rA * BK + (((q2 >> 2) ^ ((rA >> 1) & 3)) * 8) + (q2 & 3) * 2;

    // per-lane B-frag base; + tIdx*16384 + jn*512 (bf16 units) per step
    const bf16* gBf = Wf + ((size_t)((wn >> 4) * 64 + lane)) * 8;

    bf16* const AsArr[4] = {As0, As1, As2, As3};

    f32x4 acc[4][2] = {};
    bf16x8 brA[2], brB[2];   // B-frag double buffer (parity = t&1)
    uint32_t vpk[2][4][2];   // [chunk parity][channel-pair][element 0..1]
    float xe[2];

    auto loadB = [&](bf16x8 (&dst)[2], int tIdx) {
        const bf16* src = gBf + (size_t)tIdx * 16384;
#pragma unroll
        for (int jn = 0; jn < 2; jn++)
            dst[jn] = *(const bf16x8*)(src + jn * 512);
    };
    // pack spline channel j (0..7) of this thread's 2 elems into 4B
    auto write_pack = [&](bf16* slab, const uint32_t (&P)[4][2], int j) {
        const int pr = j >> 1;
        uint32_t lo = P[pr][0], hi = P[pr][1];
        uint32_t o = (j & 1) ? ((lo >> 16) | (hi & 0xFFFF0000u))
                             : ((lo & 0xFFFFu) | (hi << 16));
        *(uint32_t*)(slab + awo) = o;
    };
    auto write_silu = [&](bf16* slab) {
        float s0 = xe[0] * __builtin_amdgcn_rcpf(1.0f + __expf(-xe[0]));
        float s1 = xe[1] * __builtin_amdgcn_rcpf(1.0f + __expf(-xe[1]));
        *(uint32_t*)(slab + awo) = pk2(s0, s1);
    };
    auto domfma = [&](bf16x8 (&a)[4], bf16x8 (&b)[2]) {
        __builtin_amdgcn_s_setprio(1);
#pragma unroll
        for (int im = 0; im < 4; im++)
#pragma unroll
            for (int jn = 0; jn < 2; jn++)
                acc[im][jn] = __builtin_amdgcn_mfma_f32_16x16x32_bf16(
                    a[im], b[jn], acc[im][jn], 0, 0, 0);
        __builtin_amdgcn_s_setprio(0);
    };

    // ---- prologue: B t=0 -> brA; x chunk0; features c0; As slabs 0,1 ----
    {
        loadB(brA, 0);                // (f=0,c=0) -> tIdx 0
        float2 a = *(const float2*)xrow;
        xe[0] = a.x; xe[1] = a.y;
#pragma unroll
        for (int e = 0; e < 2; e++) {
            uint32_t o4[4];
            spline_pairs(xe[e], o4);
            vpk[0][0][e]=o4[0]; vpk[0][1][e]=o4[1];
            vpk[0][2][e]=o4[2]; vpk[0][3][e]=o4[3];
        }
        write_silu(As0);              // step 0 = (c0, f0) silu
        write_pack(As1, vpk[0], 0);   // step 1 = (c0, f1) spline channel 0
        BARA;
    }

    auto step_body = [&](auto c4v, auto fv, int c) {
        constexpr int C4 = decltype(c4v)::value;   // c mod 4
        constexpr int F  = decltype(fv)::value;    // 0..8
        constexpr int PC = C4 & 1;
        constexpr int TP = (C4 + F) & 1;           // t&1: breg parity
        constexpr int AR = (C4 + F) & 3;           // As read  = t mod 4
        constexpr int AW = (C4 + F + 2) & 3;       // As write = (t+2) mod 4

        // (0) x prefetch for chunk c+1
        if (F == 0 && c < 15) {
            float2 a = *(const float2*)(xrow + (c + 1) * 32);
            xe[0] = a.x; xe[1] = a.y;
        }
        // (1) B-frag register loads for step t+1 (issue early, use next step)
        if (!(c == 15 && F == 8)) {
            const int tN = (F < 8) ? ((F + 1) * 16 + c) : (c + 1);
            if constexpr (TP == 0) loadB(brB, tN);
            else                   loadB(brA, tN);
        }
        // (2) A-frag ds_reads (all waves read the same 64 rows)
        bf16x8 af[4];
#pragma unroll
        for (int tt = 0; tt < 4; tt++)
            af[tt] = *(const bf16x8*)(AsArr[AR] + tt * 16 * BK + aoff);

        // (3) pipelined featurize: elem F-1 of chunk c+1 (2 elems, F=1..2)
        if constexpr (F >= 1 && F <= 2) {
            if (c < 15) {
                uint32_t o4[4];
                spline_pairs(xe[F - 1], o4);
                vpk[PC ^ 1][0][F-1]=o4[0]; vpk[PC ^ 1][1][F-1]=o4[1];
                vpk[PC ^ 1][2][F-1]=o4[2]; vpk[PC ^ 1][3][F-1]=o4[3];
            }
        }
        // (4) As write for step t+2
        if constexpr (F <= 6) {
            write_pack(AsArr[AW], vpk[PC], F + 1);          // (c, F+2) -> j=F+1
        } else if constexpr (F == 7) {
            if (c < 15) write_silu(AsArr[AW]);              // (c+1, 0) silu
        } else {
            if (c < 15) write_pack(AsArr[AW], vpk[PC ^ 1], 0); // (c+1, 1) -> j=0
        }

        // (5) MFMA cluster
        if constexpr (TP == 0) domfma(af, brA);
        else                   domfma(af, brB);

        // (6) barrier at interval (odd-t) ends; protects As only (lgkm drain).
        if constexpr (TP == 1) {
            if (!(c == 15 && F == 8)) BARA;    // final step: no barrier
        }
    };

#define IC(n) std::integral_constant<int,(n)>{}
    auto chunk_body = [&](auto c4v, int c) {
        step_body(c4v, IC(0), c); step_body(c4v, IC(1), c); step_body(c4v, IC(2), c);
        step_body(c4v, IC(3), c); step_body(c4v, IC(4), c); step_body(c4v, IC(5), c);
        step_body(c4v, IC(6), c); step_body(c4v, IC(7), c); step_body(c4v, IC(8), c);
    };

    for (int cc = 0; cc < 16; cc += 4) {
        chunk_body(IC(0), cc);
        chunk_body(IC(1), cc + 1);
        chunk_body(IC(2), cc + 2);
        chunk_body(IC(3), cc + 3);
    }
#undef IC

    // C/D layout: col = lane&15, row = quad*4 + reg   [measured m89/m91]
#pragma unroll
    for (int im = 0; im < 4; im++) {
        const int rbase = m0 + im * 16 + quad * 4;
#pragma unroll
        for (int jn = 0; jn < 2; jn++) {
            const int col = wn + jn * 16 + l15;
#pragma unroll
            for (int rr = 0; rr < 4; rr++)
                C[(size_t)(rbase + rr) * O_DIM + col] = acc[im][jn][rr];
        }
    }
}

extern "C" void kernel_launch(void* const* d_in, const int* in_sizes, int n_in,
                              void* d_out, int out_size, void* d_ws, size_t ws_size,
                              hipStream_t stream) {
    const float* x  = (const float*)d_in[0];
    const float* bw = (const float*)d_in[1];
    const float* sw = (const float*)d_in[2];
    float* out = (float*)d_out;

    const size_t Wbytes = (size_t)144 * 32 * 64 * 8 * sizeof(bf16);  // 4.7 MB
    if (ws_size < Wbytes) return;
    bf16* W = (bf16*)d_ws;

    pack_w_kernel<<<(O_DIM * 64 + 255) / 256, 256, 0, stream>>>(bw, sw, W);
    gemm_fused_kernel<<<dim3(B_ROWS / BM), dim3(1024), 0, stream>>>(x, W, out);
}

// Round 10
// 153.385 us; speedup vs baseline: 1.0095x; 1.0095x over previous
//
#include <hip/hip_runtime.h>
#include <cstdint>
#include <cstddef>
#include <type_traits>

#define B_ROWS 16384
#define D_DIM  512
#define O_DIM  512
#define BM 64
#define BN 512
#define BK 32
// W repacked fragment-major: Wf[tIdx=f*16+c][cb=o/16][lane][8 bf16]
// (tIdx<144, cb<32, lane<64). A wave's B-fragment (16 cols x 8 k) is the
// contiguous 1KB chunk at ((tIdx*32+cb)*64)*8 -- one coalesced
// global_load_dwordx4 per lane, straight to VGPR.

typedef __bf16 bf16;
typedef __attribute__((ext_vector_type(8))) bf16  bf16x8;
typedef __attribute__((ext_vector_type(4))) float f32x4;

__device__ __forceinline__ uint32_t pk2(float a, float b) {
    uint16_t ua = __builtin_bit_cast(uint16_t, (__bf16)a);
    uint16_t ub = __builtin_bit_cast(uint16_t, (__bf16)b);
    return (uint32_t)ua | ((uint32_t)ub << 16);
}

// Spline channels b0..b7 for one element as 4 packed bf16 pair-regs.
__device__ __forceinline__ void spline_pairs(float xv, uint32_t out[4]) {
    float xn = fminf(fmaxf(xv, -2.0f), 2.0f);
    float t  = (xn + 3.2f) * 2.5f;        // in [3,13]
    int   j0 = (int)t;                    // t>0 so trunc==floor
    float u  = t - (float)j0;
    float u2 = u * u, u3 = u2 * u, omu = 1.0f - u;
    const float s6 = 1.0f / 6.0f;
    float w0 = omu * omu * omu * s6;
    float w1 = (3.0f * u3 - 6.0f * u2 + 4.0f) * s6;
    float w2 = (-3.0f * u3 + 3.0f * u2 + 3.0f * u + 1.0f) * s6;
    float w3 = u3 * s6;
    uint64_t W64 = ((uint64_t)pk2(w2, w3) << 32) | pk2(w0, w1);
    int sh = (j0 - 3) * 16;               // 0..160
    uint64_t lo = W64 << (sh & 63);
    uint64_t hi = W64 >> ((64 - sh) & 63);
    uint32_t lo_lo = (uint32_t)lo, lo_hi = (uint32_t)(lo >> 32);
    uint32_t hi_lo = (uint32_t)hi, hi_hi = (uint32_t)(hi >> 32);
    bool lt64 = sh < 64, eq0 = (sh == 0), lt128 = sh < 128;
    out[0] = lt64 ? lo_lo : 0u;
    out[1] = lt64 ? lo_hi : 0u;
    out[2] = lt64 ? (eq0 ? 0u : hi_lo) : (lt128 ? lo_lo : 0u);
    out[3] = lt64 ? (eq0 ? 0u : hi_hi) : (lt128 ? lo_hi : 0u);
}

// R18 pack_w v3: LDS-transpose pack. One block per (cb, c): cb=o-block/16,
// c=k-chunk/16. Stage bw tile (16x32 f32, 2KB) + sw tile (16x32x8 f32, 16KB)
// with fully-coalesced float4 row reads, then emit the 9x64 output granules
// as contiguous 1KB-per-wave stores. Both sides coalesced; 13.5MB traffic
// total -> ~3-6us (v1: 128-block launch, ~70us latency-bound; v2: scattered
// 32B-stride sw reads, ~16x line amplification).
// Output bytes identical to v1/v2:
//   granule g = ((f*16+c)*32+cb)*64 + ln; o = cb*16+(ln&15); i0 = c*32+(ln>>4)*8
//   W[g*8+e] = f==0 ? bf16(bw[o*512+i0+e]) : bf16(sw[(o*512+i0+e)*8 + f-1])
__global__ __launch_bounds__(256)
void pack_w_kernel(const float* __restrict__ bw,
                   const float* __restrict__ sw,
                   bf16* __restrict__ W) {
    __shared__ float sbw[16][32];        // 2 KB
    __shared__ float ssw[16][32][8];     // 16 KB

    const int tid = threadIdx.x;
    const int cb  = blockIdx.x >> 4;     // 0..31
    const int c   = blockIdx.x & 15;     // 0..15

    // stage bw: 512 floats = 128 float4 (threads 0..127)
    if (tid < 128) {
        const int o_l = tid >> 3, l8 = tid & 7;
        float4 v = *(const float4*)(bw + (size_t)(cb * 16 + o_l) * D_DIM + c * 32 + l8 * 4);
        sbw[o_l][l8 * 4 + 0] = v.x; sbw[o_l][l8 * 4 + 1] = v.y;
        sbw[o_l][l8 * 4 + 2] = v.z; sbw[o_l][l8 * 4 + 3] = v.w;
    }
    // stage sw: 16 rows x 256 contiguous floats; 4 rows per iteration
    {
        const int r   = tid >> 6;        // 0..3
        const int l64 = tid & 63;        // 0..63
#pragma unroll
        for (int og = 0; og < 4; og++) {
            const int o_l = og * 4 + r;
            float4 v = *(const float4*)(sw + ((size_t)(cb * 16 + o_l) * D_DIM + c * 32) * 8 + l64 * 4);
            float* d = &ssw[o_l][l64 >> 1][(l64 & 1) * 4];
            d[0] = v.x; d[1] = v.y; d[2] = v.z; d[3] = v.w;
        }
    }
    __syncthreads();

    // emit 576 granules (f=0..8, ln=0..63); wave-contiguous 16B stores
#pragma unroll
    for (int rep = 0; rep < 3; rep++) {
        const int g4 = rep * 256 + tid;
        if (g4 < 576) {
            const int f    = g4 >> 6;        // 0..8
            const int ln   = g4 & 63;
            const int o_l  = ln & 15;
            const int i0_l = (ln >> 4) * 8;
            bf16 ob[8];
            if (f == 0) {
#pragma unroll
                for (int e = 0; e < 8; e++)
                    ob[e] = (bf16)sbw[o_l][i0_l + e];
            } else {
#pragma unroll
                for (int e = 0; e < 8; e++)
                    ob[e] = (bf16)ssw[o_l][i0_l + e][f - 1];
            }
            const size_t g = ((size_t)((f * 16 + c) * 32 + cb)) * 64 + ln;
            *(bf16x8*)(W + g * 8) = *(const bf16x8*)ob;
        }
    }
}

// R18 gemm: R16 structure with ALL raw asm barriers replaced by
// __syncthreads() (compiler-managed waitcnt+barrier). R9's post-timing
// divergence was deterministic and entered with R9's changes; the inline-asm
// lgkm fence class (rule #18/#19: asm waitcnt safety depends on compiler
// scheduling, perturbable by co-compiled kernels) is eliminated wholesale.
// Cost: syncthreads also drains vmcnt -> odd-step B-loads lose ~200cyc of
// overlap; bounded ~5us. Everything else identical to R16 (green in R8):
// 1024 thr = 16 waves = 4/SIMD, wave tile 64x32, B@L2->VGPR dbuf dist 1,
// As 4 slabs write-dist 2, barrier every 2 steps.
#define BARA __syncthreads()

__global__ __launch_bounds__(1024, 4)
void gemm_fused_kernel(const float* __restrict__ x, const bf16* __restrict__ Wf,
                       float* __restrict__ C) {
    __shared__ __align__(16) bf16 As0[BM * BK], As1[BM * BK], As2[BM * BK], As3[BM * BK];

    const int tid  = threadIdx.x;
    const int bid  = blockIdx.x;
    const int m0   = bid * BM;
    const int wave = tid >> 6;
    const int lane = tid & 63;
    const int wn   = wave * 32;          // 16 waves cover N=512
    const int l15  = lane & 15;
    const int quad = lane >> 4;
    const int swz  = (l15 >> 1) & 3;
    const int aoff = l15 * BK + (quad ^ swz) * 8;

    // featurize: thread owns (row rA, 2 i's at sixteenth q2 of the 32-chunk)
    const int rA = tid >> 4;             // 0..63
    const int q2 = tid & 15;             // 0..15
    const float* xrow = x + (size_t)(m0 + rA) * D_DIM + q2 * 2;
    // 4B write: slot (q2>>2) XOR-swizzled to match aoff read swizzle,
    // sub-offset (q2&3)*2 within the 8-elem slot
    const int awo = rA * BK + (((q2 >> 2) ^ ((rA >> 1) & 3)) * 8) + (q2 & 3) * 2;

    // per-lane B-frag base; + tIdx*16384 + jn*512 (bf16 units) per step
    const bf16* gBf = Wf + ((size_t)((wn >> 4) * 64 + lane)) * 8;

    bf16* const AsArr[4] = {As0, As1, As2, As3};

    f32x4 acc[4][2] = {};
    bf16x8 brA[2], brB[2];   // B-frag double buffer (parity = t&1)
    uint32_t vpk[2][4][2];   // [chunk parity][channel-pair][element 0..1]
    float xe[2];

    auto loadB = [&](bf16x8 (&dst)[2], int tIdx) {
        const bf16* src = gBf + (size_t)tIdx * 16384;
#pragma unroll
        for (int jn = 0; jn < 2; jn++)
            dst[jn] = *(const bf16x8*)(src + jn * 512);
    };
    // pack spline channel j (0..7) of this thread's 2 elems into 4B
    auto write_pack = [&](bf16* slab, const uint32_t (&P)[4][2], int j) {
        const int pr = j >> 1;
        uint32_t lo = P[pr][0], hi = P[pr][1];
        uint32_t o = (j & 1) ? ((lo >> 16) | (hi & 0xFFFF0000u))
                             : ((lo & 0xFFFFu) | (hi << 16));
        *(uint32_t*)(slab + awo) = o;
    };
    auto write_silu = [&](bf16* slab) {
        float s0 = xe[0] * __builtin_amdgcn_rcpf(1.0f + __expf(-xe[0]));
        float s1 = xe[1] * __builtin_amdgcn_rcpf(1.0f + __expf(-xe[1]));
        *(uint32_t*)(slab + awo) = pk2(s0, s1);
    };
    auto domfma = [&](bf16x8 (&a)[4], bf16x8 (&b)[2]) {
        __builtin_amdgcn_s_setprio(1);
#pragma unroll
        for (int im = 0; im < 4; im++)
#pragma unroll
            for (int jn = 0; jn < 2; jn++)
                acc[im][jn] = __builtin_amdgcn_mfma_f32_16x16x32_bf16(
                    a[im], b[jn], acc[im][jn], 0, 0, 0);
        __builtin_amdgcn_s_setprio(0);
    };

    // ---- prologue: B t=0 -> brA; x chunk0; features c0; As slabs 0,1 ----
    {
        loadB(brA, 0);                // (f=0,c=0) -> tIdx 0
        float2 a = *(const float2*)xrow;
        xe[0] = a.x; xe[1] = a.y;
#pragma unroll
        for (int e = 0; e < 2; e++) {
            uint32_t o4[4];
            spline_pairs(xe[e], o4);
            vpk[0][0][e]=o4[0]; vpk[0][1][e]=o4[1];
            vpk[0][2][e]=o4[2]; vpk[0][3][e]=o4[3];
        }
        write_silu(As0);              // step 0 = (c0, f0) silu
        write_pack(As1, vpk[0], 0);   // step 1 = (c0, f1) spline channel 0
        BARA;
    }

    auto step_body = [&](auto c4v, auto fv, int c) {
        constexpr int C4 = decltype(c4v)::value;   // c mod 4
        constexpr int F  = decltype(fv)::value;    // 0..8
        constexpr int PC = C4 & 1;
        constexpr int TP = (C4 + F) & 1;           // t&1: breg parity
        constexpr int AR = (C4 + F) & 3;           // As read  = t mod 4
        constexpr int AW = (C4 + F + 2) & 3;       // As write = (t+2) mod 4

        // (0) x prefetch for chunk c+1
        if (F == 0 && c < 15) {
            float2 a = *(const float2*)(xrow + (c + 1) * 32);
            xe[0] = a.x; xe[1] = a.y;
        }
        // (1) B-frag register loads for step t+1 (issue early, use next step)
        if (!(c == 15 && F == 8)) {
            const int tN = (F < 8) ? ((F + 1) * 16 + c) : (c + 1);
            if constexpr (TP == 0) loadB(brB, tN);
            else                   loadB(brA, tN);
        }
        // (2) A-frag ds_reads (all waves read the same 64 rows)
        bf16x8 af[4];
#pragma unroll
        for (int tt = 0; tt < 4; tt++)
            af[tt] = *(const bf16x8*)(AsArr[AR] + tt * 16 * BK + aoff);

        // (3) pipelined featurize: elem F-1 of chunk c+1 (2 elems, F=1..2)
        if constexpr (F >= 1 && F <= 2) {
            if (c < 15) {
                uint32_t o4[4];
                spline_pairs(xe[F - 1], o4);
                vpk[PC ^ 1][0][F-1]=o4[0]; vpk[PC ^ 1][1][F-1]=o4[1];
                vpk[PC ^ 1][2][F-1]=o4[2]; vpk[PC ^ 1][3][F-1]=o4[3];
            }
        }
        // (4) As write for step t+2
        if constexpr (F <= 6) {
            write_pack(AsArr[AW], vpk[PC], F + 1);          // (c, F+2) -> j=F+1
        } else if constexpr (F == 7) {
            if (c < 15) write_silu(AsArr[AW]);              // (c+1, 0) silu
        } else {
            if (c < 15) write_pack(AsArr[AW], vpk[PC ^ 1], 0); // (c+1, 1) -> j=0
        }

        // (5) MFMA cluster
        if constexpr (TP == 0) domfma(af, brA);
        else                   domfma(af, brB);

        // (6) barrier at interval (odd-t) ends; __syncthreads (full drain).
        if constexpr (TP == 1) {
            if (!(c == 15 && F == 8)) BARA;    // final step: no barrier
        }
    };

#define IC(n) std::integral_constant<int,(n)>{}
    auto chunk_body = [&](auto c4v, int c) {
        step_body(c4v, IC(0), c); step_body(c4v, IC(1), c); step_body(c4v, IC(2), c);
        step_body(c4v, IC(3), c); step_body(c4v, IC(4), c); step_body(c4v, IC(5), c);
        step_body(c4v, IC(6), c); step_body(c4v, IC(7), c); step_body(c4v, IC(8), c);
    };

    for (int cc = 0; cc < 16; cc += 4) {
        chunk_body(IC(0), cc);
        chunk_body(IC(1), cc + 1);
        chunk_body(IC(2), cc + 2);
        chunk_body(IC(3), cc + 3);
    }
#undef IC

    // C/D layout: col = lane&15, row = quad*4 + reg   [measured m89/m91]
#pragma unroll
    for (int im = 0; im < 4; im++) {
        const int rbase = m0 + im * 16 + quad * 4;
#pragma unroll
        for (int jn = 0; jn < 2; jn++) {
            const int col = wn + jn * 16 + l15;
#pragma unroll
            for (int rr = 0; rr < 4; rr++)
                C[(size_t)(rbase + rr) * O_DIM + col] = acc[im][jn][rr];
        }
    }
}

extern "C" void kernel_launch(void* const* d_in, const int* in_sizes, int n_in,
                              void* d_out, int out_size, void* d_ws, size_t ws_size,
                              hipStream_t stream) {
    const float* x  = (const float*)d_in[0];
    const float* bw = (const float*)d_in[1];
    const float* sw = (const float*)d_in[2];
    float* out = (float*)d_out;

    const size_t Wbytes = (size_t)144 * 32 * 64 * 8 * sizeof(bf16);  // 4.7 MB
    if (ws_size < Wbytes) return;
    bf16* W = (bf16*)d_ws;

    pack_w_kernel<<<dim3(512), dim3(256), 0, stream>>>(bw, sw, W);
    gemm_fused_kernel<<<dim3(B_ROWS / BM), dim3(1024), 0, stream>>>(x, W, out);
}